// Round 9
// baseline (867.106 us; speedup 1.0000x reference)
//
#include <hip/hip_runtime.h>
#include <hip/hip_fp16.h>

#define NNODES 100000
#define NEDGES 1600000

#define BSHIFT 7
#define BSIZE  128                         // nodes per bucket
#define NBUCK  ((NNODES + BSIZE - 1) >> BSHIFT)   // 782
#define BIN_EPT  16
#define BIN_TILE (256 * BIN_EPT)           // 4096 edges per bin block
#define NBINBLK  ((NEDGES + BIN_TILE - 1) / BIN_TILE)   // 391

static constexpr float EPS = 1e-12f;

__device__ __forceinline__ float2 h2f(unsigned u) {
    __half2 h = __builtin_bit_cast(__half2, u);
    return __half22float2(h);
}

#if defined(__has_builtin)
#if __has_builtin(__builtin_amdgcn_fdot2)
#define HAVE_FDOT2 1
#endif
#endif

__device__ __forceinline__ float dot8(uint2 a, uint2 b) {
#ifdef HAVE_FDOT2
    typedef _Float16 h2v __attribute__((ext_vector_type(2)));
    h2v ax = __builtin_bit_cast(h2v, a.x), ay = __builtin_bit_cast(h2v, a.y);
    h2v bx = __builtin_bit_cast(h2v, b.x), by = __builtin_bit_cast(h2v, b.y);
    return __builtin_amdgcn_fdot2(ax, bx,
           __builtin_amdgcn_fdot2(ay, by, 0.f, false), false);
#else
    float2 a01 = h2f(a.x), a23 = h2f(a.y);
    float2 b01 = h2f(b.x), b23 = h2f(b.y);
    return a01.x * b01.x + a01.y * b01.y + a23.x * b23.x + a23.y * b23.y;
#endif
}

// ---------------- bucket build (no per-node CSR needed) ----------------

__global__ __launch_bounds__(256) void k_bhist(
    const int* __restrict__ dst, int* __restrict__ bcnt)
{
    __shared__ int cnt[NBUCK];
    for (int i = threadIdx.x; i < NBUCK; i += 256) cnt[i] = 0;
    __syncthreads();
    int base = blockIdx.x * BIN_TILE;
    #pragma unroll
    for (int i = 0; i < BIN_EPT; ++i) {
        int k = base + i * 256 + threadIdx.x;
        if (k < NEDGES) atomicAdd(&cnt[dst[k] >> BSHIFT], 1);
    }
    __syncthreads();
    for (int i = threadIdx.x; i < NBUCK; i += 256)
        if (cnt[i]) atomicAdd(&bcnt[i], cnt[i]);
}

__global__ __launch_bounds__(1024) void k_bscan(
    const int* __restrict__ bcnt, int* __restrict__ bbase,
    int* __restrict__ bcur)
{
    __shared__ int ls[1024];
    int t = threadIdx.x;
    ls[t] = (t < NBUCK) ? bcnt[t] : 0;
    __syncthreads();
    for (int off = 1; off < 1024; off <<= 1) {
        int u = (t >= off) ? ls[t - off] : 0;
        __syncthreads();
        ls[t] += u;
        __syncthreads();
    }
    if (t < NBUCK) {
        int b = (t == 0) ? 0 : ls[t - 1];
        bbase[t] = b;
        bcur[t]  = b;
    }
}

// bin edges bucket-contiguously: packed = (dst & 127)<<17 | src
__global__ __launch_bounds__(256) void k_bin(
    const int* __restrict__ src, const int* __restrict__ dst,
    int* __restrict__ bcur, unsigned* __restrict__ packed)
{
    __shared__ int cnt[NBUCK];
    __shared__ int gb[NBUCK];
    for (int i = threadIdx.x; i < NBUCK; i += 256) cnt[i] = 0;
    __syncthreads();
    unsigned pk[BIN_EPT];
    int bk[BIN_EPT];
    int base = blockIdx.x * BIN_TILE;
    #pragma unroll
    for (int i = 0; i < BIN_EPT; ++i) {
        int k = base + i * 256 + threadIdx.x;
        bk[i] = -1;
        if (k < NEDGES) {
            int d = dst[k], s = src[k];
            bk[i] = d >> BSHIFT;
            pk[i] = ((unsigned)(d & (BSIZE - 1)) << 17) | (unsigned)s;
            atomicAdd(&cnt[bk[i]], 1);
        }
    }
    __syncthreads();
    for (int i = threadIdx.x; i < NBUCK; i += 256) {
        int c = cnt[i];
        gb[i] = c ? atomicAdd(&bcur[i], c) : 0;
        cnt[i] = 0;
    }
    __syncthreads();
    #pragma unroll
    for (int i = 0; i < BIN_EPT; ++i) {
        if (bk[i] >= 0) {
            int pos = gb[bk[i]] + atomicAdd(&cnt[bk[i]], 1);
            packed[pos] = pk[i];
        }
    }
}

// ---------------- compute kernels ----------------

// hn16[N,32] = fp16 normalized relu(feat @ w1^T + b1); nrm[N] = max(||h||,eps)
__global__ __launch_bounds__(256) void k_lin1(
    const float* __restrict__ feat, const float* __restrict__ w1,
    const float* __restrict__ b1, __half* __restrict__ hn16,
    float* __restrict__ nrm)
{
    __shared__ float w1s[32][129];
    __shared__ float fs[8][128];
    for (int i = threadIdx.x; i < 32 * 128; i += 256)
        w1s[i >> 7][i & 127] = w1[i];
    int r = threadIdx.x >> 5, c = threadIdx.x & 31;
    float bc = b1[c];
    const int ntiles = (NNODES + 7) / 8;
    for (int tile = blockIdx.x; tile < ntiles; tile += gridDim.x) {
        int row0 = tile * 8;
        __syncthreads();
        for (int i = threadIdx.x; i < 8 * 128; i += 256) {
            int rr = row0 + (i >> 7);
            fs[i >> 7][i & 127] = (rr < NNODES) ? feat[rr * 128 + (i & 127)] : 0.f;
        }
        __syncthreads();
        int row = row0 + r;
        float acc = bc;
        #pragma unroll
        for (int k = 0; k < 128; ++k) acc += fs[r][k] * w1s[c][k];
        acc = fmaxf(acc, 0.f);
        float ss = acc * acc;
        #pragma unroll
        for (int off = 16; off > 0; off >>= 1) ss += __shfl_xor(ss, off);
        if (row < NNODES) {
            float n = fmaxf(sqrtf(ss), EPS);
            hn16[(size_t)row * 32 + c] = __float2half(acc / n);
            if (c == 0) nrm[row] = n;
        }
    }
}

// Edge-throughput AGNN: one block per 128-node bucket. Dst rows staged in
// LDS; w*h_src accumulated via LDS float atomics (constant-shift softmax =>
// single pass, no max). 8-lane groups, 2-edge unroll => 64 indep chains/block.
template <bool FUSED>
__global__ __launch_bounds__(256) void k_agnn(
    const __half* __restrict__ hn16, const float* __restrict__ nrm,
    const unsigned* __restrict__ packed, const int* __restrict__ bbase,
    const int* __restrict__ bcnt, const float* __restrict__ betas, int layer,
    __half* __restrict__ hnout, float* __restrict__ nout,
    const float* __restrict__ w2, const float* __restrict__ b2,
    float* __restrict__ out)
{
    __shared__ float accs[BSIZE][33];   // stride-33: spread banks
    __shared__ float dens[BSIZE];
    __shared__ uint2 rows[BSIZE][9];    // dst hn rows (f16x4 per uint2), pad
    __shared__ float w2s[64][33];       // FUSED only

    int b = blockIdx.x, t = threadIdx.x;
    int base = bbase[b], n = bcnt[b];
    int node0 = b * BSIZE;

    for (int i = t; i < BSIZE * 33; i += 256) (&accs[0][0])[i] = 0.f;
    if (t < BSIZE) dens[t] = 0.f;
    const uint2* hrow = reinterpret_cast<const uint2*>(hn16);
    for (int i = t; i < BSIZE * 8; i += 256) {
        int r = i >> 3, c = i & 7;
        int gn = node0 + r;
        uint2 v = make_uint2(0u, 0u);
        if (gn < NNODES) v = hrow[(size_t)gn * 8 + c];
        rows[r][c] = v;
    }
    if (FUSED) {
        for (int i = t; i < 64 * 32; i += 256) w2s[i >> 5][i & 31] = w2[i];
    }
    __syncthreads();

    int g = t >> 3, c4 = t & 7;
    float beta = betas[layer];
    float absb = fabsf(beta);
    int end = base + n;

    for (int i0 = base + g; i0 < end; i0 += 64) {
        int i1 = i0 + 32;
        bool has1 = (i1 < end);
        unsigned u0 = packed[i0];
        unsigned u1 = has1 ? packed[i1] : u0;
        int d0 = u0 >> 17, s0 = (int)(u0 & 0x1FFFFu);
        int d1 = u1 >> 17, s1 = (int)(u1 & 0x1FFFFu);
        uint2 q0 = hrow[(size_t)s0 * 8 + c4];
        uint2 q1 = hrow[(size_t)s1 * 8 + c4];
        float n0 = nrm[s0], n1 = nrm[s1];
        uint2 dq0 = rows[d0][c4];
        uint2 dq1 = rows[d1][c4];
        float p0 = dot8(q0, dq0);
        float p1 = dot8(q1, dq1);
        #pragma unroll
        for (int off = 4; off > 0; off >>= 1) {
            p0 += __shfl_xor(p0, off);
            p1 += __shfl_xor(p1, off);
        }
        float w0 = __expf(fmaf(beta, p0, -absb));   // exp(e - |beta|)
        float w1 = __expf(fmaf(beta, p1, -absb));
        float wn0 = w0 * n0, wn1 = w1 * n1;
        float2 a01 = h2f(q0.x), a23 = h2f(q0.y);
        float* ap = &accs[d0][c4 * 4];
        atomicAdd(ap + 0, wn0 * a01.x);
        atomicAdd(ap + 1, wn0 * a01.y);
        atomicAdd(ap + 2, wn0 * a23.x);
        atomicAdd(ap + 3, wn0 * a23.y);
        if (c4 == 0) atomicAdd(&dens[d0], w0);
        if (has1) {
            float2 b01 = h2f(q1.x), b23 = h2f(q1.y);
            float* bp = &accs[d1][c4 * 4];
            atomicAdd(bp + 0, wn1 * b01.x);
            atomicAdd(bp + 1, wn1 * b01.y);
            atomicAdd(bp + 2, wn1 * b23.x);
            atomicAdd(bp + 3, wn1 * b23.y);
            if (c4 == 0) atomicAdd(&dens[d1], w1);
        }
    }
    __syncthreads();

    // normalize: o = relu(acc/den)
    if (t < BSIZE) {
        int node = node0 + t;
        float inv = 1.f / fmaxf(dens[t], EPS);
        float o[32];
        float ss = 0.f;
        #pragma unroll
        for (int j = 0; j < 32; ++j) {
            o[j] = fmaxf(accs[t][j] * inv, 0.f);
            ss += o[j] * o[j];
        }
        if (!FUSED) {
            if (node < NNODES) {
                float nn = fmaxf(sqrtf(ss), EPS);
                float rn = 1.f / nn;
                nout[node] = nn;
                uint4 qv[4];                       // FULL 64B row (32 halves)
                unsigned* qw = reinterpret_cast<unsigned*>(qv);
                #pragma unroll
                for (int j = 0; j < 16; ++j) {
                    __half2 hh = __floats2half2_rn(o[2 * j] * rn, o[2 * j + 1] * rn);
                    qw[j] = __builtin_bit_cast(unsigned, hh);
                }
                uint4* dst4 = reinterpret_cast<uint4*>(hnout + (size_t)node * 32);
                dst4[0] = qv[0];
                dst4[1] = qv[1];
                dst4[2] = qv[2];
                dst4[3] = qv[3];
            }
        } else {
            #pragma unroll
            for (int j = 0; j < 32; ++j) accs[t][j] = o[j];   // store o back
        }
    }

    if (FUSED) {
        __syncthreads();
        int lane = t & 63, wid = t >> 6;
        float b2l = b2[lane];
        for (int p = 0; p < 32; ++p) {
            int ln = p * 4 + wid;
            int node = node0 + ln;
            float a2 = b2l;
            #pragma unroll
            for (int k = 0; k < 32; ++k) a2 += accs[ln][k] * w2s[lane][k];
            float mx = a2;
            #pragma unroll
            for (int off = 32; off > 0; off >>= 1)
                mx = fmaxf(mx, __shfl_xor(mx, off));
            float ex = __expf(a2 - mx);
            float sm = ex;
            #pragma unroll
            for (int off = 32; off > 0; off >>= 1)
                sm += __shfl_xor(sm, off);
            if (node < NNODES)
                out[(size_t)node * 64 + lane] = a2 - mx - __logf(sm);
        }
    }
}

extern "C" void kernel_launch(void* const* d_in, const int* in_sizes, int n_in,
                              void* d_out, int out_size, void* d_ws, size_t ws_size,
                              hipStream_t stream)
{
    const float* feat  = (const float*)d_in[0];
    const int*   src   = (const int*)d_in[1];
    const int*   dst   = (const int*)d_in[2];
    const float* w1    = (const float*)d_in[3];
    const float* b1    = (const float*)d_in[4];
    const float* betas = (const float*)d_in[5];
    const float* w2    = (const float*)d_in[6];
    const float* b2    = (const float*)d_in[7];
    float* out = (float*)d_out;

    // workspace (~20.6 MB): hnA[6.4] hnB[6.4] nA nB packed[6.4] bcnt/bbase/bcur
    __half*   hnA    = (__half*)d_ws;
    __half*   hnB    = hnA + (size_t)NNODES * 32;
    float*    nA     = (float*)(hnB + (size_t)NNODES * 32);
    float*    nB     = nA + NNODES;
    unsigned* packed = (unsigned*)(nB + NNODES);
    int*      bcnt   = (int*)(packed + NEDGES);
    int*      bbase  = bcnt + NBUCK;
    int*      bcur   = bbase + NBUCK;

    dim3 blk(256);

    // bucket build (once, shared by both layers)
    hipMemsetAsync(bcnt, 0, NBUCK * sizeof(int), stream);
    k_bhist<<<NBINBLK, blk, 0, stream>>>(dst, bcnt);
    k_bscan<<<1, 1024, 0, stream>>>(bcnt, bbase, bcur);
    k_bin<<<NBINBLK, blk, 0, stream>>>(src, dst, bcur, packed);

    k_lin1<<<2048, blk, 0, stream>>>(feat, w1, b1, hnA, nA);

    k_agnn<false><<<NBUCK, blk, 0, stream>>>(hnA, nA, packed, bbase, bcnt,
                                             betas, 0, hnB, nB,
                                             nullptr, nullptr, nullptr);
    k_agnn<true><<<NBUCK, blk, 0, stream>>>(hnB, nB, packed, bbase, bcnt,
                                            betas, 1, nullptr, nullptr,
                                            w2, b2, out);
}

// Round 10
// 219.126 us; speedup vs baseline: 3.9571x; 3.9571x over previous
//
#include <hip/hip_runtime.h>
#include <hip/hip_fp16.h>

#define NNODES 100000
#define NEDGES 1600000

#define NBUCK  ((NNODES + 511) >> 9)      // 196 buckets of 512 nodes
#define BIN_EPT  16
#define BIN_TILE (256 * BIN_EPT)          // 4096 edges per bin block
#define NBINBLK  ((NEDGES + BIN_TILE - 1) / BIN_TILE)   // 391

static_assert(NNODES % 4 == 0, "fused kernel assumes exact node quads");

static constexpr float EPS = 1e-12f;

__device__ __forceinline__ float2 h2f(unsigned u) {
    __half2 h = __builtin_bit_cast(__half2, u);
    return __half22float2(h);
}

#if defined(__has_builtin)
#if __has_builtin(__builtin_amdgcn_fdot2)
#define HAVE_FDOT2 1
#endif
#endif

__device__ __forceinline__ float dot8(uint2 a, uint2 b) {
#ifdef HAVE_FDOT2
    typedef _Float16 h2v __attribute__((ext_vector_type(2)));
    h2v ax = __builtin_bit_cast(h2v, a.x), ay = __builtin_bit_cast(h2v, a.y);
    h2v bx = __builtin_bit_cast(h2v, b.x), by = __builtin_bit_cast(h2v, b.y);
    return __builtin_amdgcn_fdot2(ax, bx,
           __builtin_amdgcn_fdot2(ay, by, 0.f, false), false);
#else
    float2 a01 = h2f(a.x), a23 = h2f(a.y);
    float2 b01 = h2f(b.x), b23 = h2f(b.y);
    return a01.x * b01.x + a01.y * b01.y + a23.x * b23.x + a23.y * b23.y;
#endif
}

// ---- DPP cross-lane reduction helpers (no LDS, no waitcnt) ----
// quad_perm xor1 = 0xB1, xor2 = 0x4E; ROW_HALF_MIRROR (0x141) == xor4 once
// quads are uniform; ROW_ROR:8 (0x128) == xor8 once 8-groups are uniform.
template <int CTRL>
__device__ __forceinline__ float dppadd(float x) {
    int y = __builtin_amdgcn_update_dpp(0, __builtin_bit_cast(int, x),
                                        CTRL, 0xF, 0xF, true);
    return x + __builtin_bit_cast(float, y);
}
template <int CTRL>
__device__ __forceinline__ float dppmax(float x) {
    int y = __builtin_amdgcn_update_dpp(0, __builtin_bit_cast(int, x),
                                        CTRL, 0xF, 0xF, true);
    return fmaxf(x, __builtin_bit_cast(float, y));
}
__device__ __forceinline__ float swz16add(float x) {   // + lane^16 (exact)
    int y = __builtin_amdgcn_ds_swizzle(__builtin_bit_cast(int, x), 0x401F);
    return x + __builtin_bit_cast(float, y);
}
__device__ __forceinline__ float swz16max(float x) {
    int y = __builtin_amdgcn_ds_swizzle(__builtin_bit_cast(int, x), 0x401F);
    return fmaxf(x, __builtin_bit_cast(float, y));
}
// sum over an 8-lane group (lanes uniform on exit)
__device__ __forceinline__ float red8(float x) {
    x = dppadd<0xB1>(x);
    x = dppadd<0x4E>(x);
    x = dppadd<0x141>(x);
    return x;
}
// combine the 8 groups of a wave (inputs 8-uniform): xor8, xor16, xor32
__device__ __forceinline__ float redg(float x) {
    x = dppadd<0x128>(x);
    x = swz16add(x);
    x += __shfl_xor(x, 32);
    return x;
}
// full 64-lane sum / max (exact)
__device__ __forceinline__ float red64(float x) {
    x = dppadd<0xB1>(x); x = dppadd<0x4E>(x);
    x = dppadd<0x141>(x); x = dppadd<0x128>(x);
    x = swz16add(x);
    x += __shfl_xor(x, 32);
    return x;
}
__device__ __forceinline__ float red64max(float x) {
    x = dppmax<0xB1>(x); x = dppmax<0x4E>(x);
    x = dppmax<0x141>(x); x = dppmax<0x128>(x);
    x = swz16max(x);
    x = fmaxf(x, __shfl_xor(x, 32));
    return x;
}
// sum over 32-lane half (lanes 0-31 pattern; exact)
__device__ __forceinline__ float red32(float x) {
    x = dppadd<0xB1>(x); x = dppadd<0x4E>(x);
    x = dppadd<0x141>(x); x = dppadd<0x128>(x);
    x = swz16add(x);
    return x;
}

// ---------------- CSR build: bucketed counting sort ----------------

__global__ __launch_bounds__(256) void k_bhist(
    const int* __restrict__ dst, int* __restrict__ bcnt)
{
    __shared__ int cnt[NBUCK];
    for (int i = threadIdx.x; i < NBUCK; i += 256) cnt[i] = 0;
    __syncthreads();
    int base = blockIdx.x * BIN_TILE;
    #pragma unroll
    for (int i = 0; i < BIN_EPT; ++i) {
        int k = base + i * 256 + threadIdx.x;
        if (k < NEDGES) atomicAdd(&cnt[dst[k] >> 9], 1);
    }
    __syncthreads();
    for (int i = threadIdx.x; i < NBUCK; i += 256)
        if (cnt[i]) atomicAdd(&bcnt[i], cnt[i]);
}

__global__ __launch_bounds__(256) void k_bscan(
    const int* __restrict__ bcnt, int* __restrict__ bbase,
    int* __restrict__ bcur, int* __restrict__ rowptr)
{
    __shared__ int ls[256];
    int t = threadIdx.x;
    ls[t] = (t < NBUCK) ? bcnt[t] : 0;
    __syncthreads();
    for (int off = 1; off < 256; off <<= 1) {
        int u = (t >= off) ? ls[t - off] : 0;
        __syncthreads();
        ls[t] += u;
        __syncthreads();
    }
    if (t < NBUCK) {
        int b = (t == 0) ? 0 : ls[t - 1];
        bbase[t] = b;
        bcur[t]  = b;
    }
    if (t == 0) rowptr[NNODES] = NEDGES;
}

// bin edges into bucket-contiguous packed[] : (dst&511)<<17 | src
__global__ __launch_bounds__(256) void k_bin(
    const int* __restrict__ src, const int* __restrict__ dst,
    int* __restrict__ bcur, unsigned* __restrict__ packed)
{
    __shared__ int cnt[NBUCK];
    __shared__ int gb[NBUCK];
    for (int i = threadIdx.x; i < NBUCK; i += 256) cnt[i] = 0;
    __syncthreads();
    unsigned pk[BIN_EPT];
    int bk[BIN_EPT];
    int base = blockIdx.x * BIN_TILE;
    #pragma unroll
    for (int i = 0; i < BIN_EPT; ++i) {
        int k = base + i * 256 + threadIdx.x;
        bk[i] = -1;
        if (k < NEDGES) {
            int d = dst[k], s = src[k];
            bk[i] = d >> 9;
            pk[i] = ((unsigned)(d & 511) << 17) | (unsigned)s;
            atomicAdd(&cnt[bk[i]], 1);
        }
    }
    __syncthreads();
    for (int i = threadIdx.x; i < NBUCK; i += 256) {
        int c = cnt[i];
        gb[i] = c ? atomicAdd(&bcur[i], c) : 0;
        cnt[i] = 0;
    }
    __syncthreads();
    #pragma unroll
    for (int i = 0; i < BIN_EPT; ++i) {
        if (bk[i] >= 0) {
            int pos = gb[bk[i]] + atomicAdd(&cnt[bk[i]], 1);
            packed[pos] = pk[i];
        }
    }
}

// one block per bucket: local count -> local scan -> rowptr + esrc scatter
__global__ __launch_bounds__(512) void k_bucket(
    const unsigned* __restrict__ packed, const int* __restrict__ bbase,
    const int* __restrict__ bcnt, int* __restrict__ rowptr,
    int* __restrict__ esrc)
{
    __shared__ int cnt[512];
    __shared__ int loc[512];
    int b = blockIdx.x, t = threadIdx.x;
    int base = bbase[b];
    int n = bcnt[b];
    cnt[t] = 0;
    __syncthreads();
    for (int i = t; i < n; i += 512)
        atomicAdd(&cnt[packed[base + i] >> 17], 1);
    __syncthreads();
    int v = cnt[t];
    loc[t] = v;
    __syncthreads();
    for (int off = 1; off < 512; off <<= 1) {
        int u = (t >= off) ? loc[t - off] : 0;
        __syncthreads();
        loc[t] += u;
        __syncthreads();
    }
    int excl = loc[t] - v;
    int node = b * 512 + t;
    if (node < NNODES) rowptr[node] = base + excl;
    cnt[t] = base + excl;          // absolute cursor
    __syncthreads();
    for (int i = t; i < n; i += 512) {
        unsigned p = packed[base + i];
        int pos = atomicAdd(&cnt[p >> 17], 1);
        esrc[pos] = (int)(p & 0x1FFFFu);
    }
}

// ---------------- compute kernels ----------------

// hn16[N,32] = fp16 normalized relu(feat @ w1^T + b1); nrm[N] = max(||h||,eps)
__global__ __launch_bounds__(256) void k_lin1(
    const float* __restrict__ feat, const float* __restrict__ w1,
    const float* __restrict__ b1, __half* __restrict__ hn16,
    float* __restrict__ nrm)
{
    __shared__ float w1s[32][129];
    __shared__ float fs[8][128];
    for (int i = threadIdx.x; i < 32 * 128; i += 256)
        w1s[i >> 7][i & 127] = w1[i];
    int r = threadIdx.x >> 5, c = threadIdx.x & 31;
    float bc = b1[c];
    const int ntiles = (NNODES + 7) / 8;
    for (int tile = blockIdx.x; tile < ntiles; tile += gridDim.x) {
        int row0 = tile * 8;
        __syncthreads();
        for (int i = threadIdx.x; i < 8 * 128; i += 256) {
            int rr = row0 + (i >> 7);
            fs[i >> 7][i & 127] = (rr < NNODES) ? feat[rr * 128 + (i & 127)] : 0.f;
        }
        __syncthreads();
        int row = row0 + r;
        float acc = bc;
        #pragma unroll
        for (int k = 0; k < 128; ++k) acc += fs[r][k] * w1s[c][k];
        acc = fmaxf(acc, 0.f);
        float ss = red32(acc * acc);          // sum over the 32 c-lanes
        if (row < NNODES) {
            float n = fmaxf(sqrtf(ss), EPS);
            hn16[(size_t)row * 32 + c] = __float2half(acc / n);
            if (c == 0) nrm[row] = n;
        }
    }
}

// One wave per destination node; 8 groups of 8 lanes (8B fp16x4 per lane),
// 2-edge unroll => 16 independent gather chains per wave.
// Rows stored normalized: e = beta*dot(hn_s,hn_d); h_s = n_s*hn_s.
// Constant-shift softmax: e in [-|beta|,|beta|] => w = exp(e-|beta|), no max.
// All reductions via DPP (no ds_bpermute in the hot path).
template <bool FUSED>
__global__ __launch_bounds__(256) void k_agnn(
    const __half* __restrict__ hn16, const float* __restrict__ nrm,
    const int* __restrict__ rowptr, const int* __restrict__ esrc,
    const float* __restrict__ betas, int layer,
    __half* __restrict__ hnout, float* __restrict__ nout,
    const float* __restrict__ w2, const float* __restrict__ b2,
    float* __restrict__ out)
{
    __shared__ float w2s[64][33];     // only used when FUSED
    __shared__ float4 osm[4][8];
    if (FUSED) {
        for (int i = threadIdx.x; i < 64 * 32; i += 256)
            w2s[i >> 5][i & 31] = w2[i];
    }
    int wid  = threadIdx.x >> 6;
    int node = blockIdx.x * 4 + wid;
    int lane = threadIdx.x & 63;
    int grp  = lane >> 3;            // 8 edge-groups
    int c4   = lane & 7;             // 8B slot (4 halves) within the 64B row

    int start = rowptr[node], end = rowptr[node + 1];

    const uint2* hrow = reinterpret_cast<const uint2*>(hn16);
    float beta = betas[layer];
    float absb = fabsf(beta);
    uint2 qd = hrow[(size_t)node * 8 + c4];
    float2 d01 = h2f(qd.x), d23 = h2f(qd.y);
    d01.x *= beta; d01.y *= beta; d23.x *= beta; d23.y *= beta;
    uint2 qdb;
    qdb.x = __builtin_bit_cast(unsigned, __floats2half2_rn(d01.x, d01.y));
    qdb.y = __builtin_bit_cast(unsigned, __floats2half2_rn(d23.x, d23.y));

    float den = 0.f;
    float4 acc = make_float4(0.f, 0.f, 0.f, 0.f);

    for (int i0 = start + grp; i0 < end; i0 += 16) {
        int i1 = i0 + 8;
        bool has1 = (i1 < end);
        int s0 = esrc[i0];
        int s1 = has1 ? esrc[i1] : s0;
        uint2 q0 = hrow[(size_t)s0 * 8 + c4];
        uint2 q1 = hrow[(size_t)s1 * 8 + c4];
        float n0 = nrm[s0], n1 = nrm[s1];
        float p0 = dot8(q0, qd);
        float p1 = dot8(q1, qd);
        p0 = red8(p0);                 // 3 DPP adds, no LDS
        p1 = red8(p1);
        float w0 = __expf(fmaf(beta, p0, -absb));   // exp(e - |beta|)
        float w1 = has1 ? __expf(fmaf(beta, p1, -absb)) : 0.f;
        float wn0 = w0 * n0, wn1 = w1 * n1;
        float2 a01 = h2f(q0.x), a23 = h2f(q0.y);
        float2 b01 = h2f(q1.x), b23 = h2f(q1.y);
        den += w0 + w1;
        acc.x += wn0 * a01.x + wn1 * b01.x;
        acc.y += wn0 * a01.y + wn1 * b01.y;
        acc.z += wn0 * a23.x + wn1 * b23.x;
        acc.w += wn0 * a23.y + wn1 * b23.y;
    }

    // merge the 8 groups: xor8 (DPP), xor16 (swizzle), xor32 (shfl)
    den   = redg(den);
    acc.x = redg(acc.x);
    acc.y = redg(acc.y);
    acc.z = redg(acc.z);
    acc.w = redg(acc.w);

    float inv = 1.f / fmaxf(den, EPS);
    float4 o;
    o.x = fmaxf(acc.x * inv, 0.f);
    o.y = fmaxf(acc.y * inv, 0.f);
    o.z = fmaxf(acc.z * inv, 0.f);
    o.w = fmaxf(acc.w * inv, 0.f);

    if (!FUSED) {
        float ss = red8(o.x * o.x + o.y * o.y + o.z * o.z + o.w * o.w);
        if (grp == 0) {
            float nn = fmaxf(sqrtf(ss), EPS);
            float rn = 1.f / nn;
            __half2 lo = __floats2half2_rn(o.x * rn, o.y * rn);
            __half2 hi = __floats2half2_rn(o.z * rn, o.w * rn);
            uint2 q;
            q.x = __builtin_bit_cast(unsigned, lo);
            q.y = __builtin_bit_cast(unsigned, hi);
            reinterpret_cast<uint2*>(hnout)[(size_t)node * 8 + c4] = q;
            if (c4 == 0) nout[node] = nn;
        }
    } else {
        if (grp == 0) osm[wid][c4] = o;
        __syncthreads();   // exact grid: all threads arrive
        const float* op = reinterpret_cast<const float*>(osm[wid]);
        float a2 = b2[lane];
        #pragma unroll
        for (int k = 0; k < 32; ++k) a2 += op[k] * w2s[lane][k];
        float mx = red64max(a2);
        float sm = red64(__expf(a2 - mx));
        out[(size_t)node * 64 + lane] = a2 - mx - __logf(sm);
    }
    (void)qdb;
}

extern "C" void kernel_launch(void* const* d_in, const int* in_sizes, int n_in,
                              void* d_out, int out_size, void* d_ws, size_t ws_size,
                              hipStream_t stream)
{
    const float* feat  = (const float*)d_in[0];
    const int*   src   = (const int*)d_in[1];
    const int*   dst   = (const int*)d_in[2];
    const float* w1    = (const float*)d_in[3];
    const float* b1    = (const float*)d_in[4];
    const float* betas = (const float*)d_in[5];
    const float* w2    = (const float*)d_in[6];
    const float* b2    = (const float*)d_in[7];
    float* out = (float*)d_out;

    // workspace: hnA[6.4MB] hnB[6.4MB] nA[N] nB[N] rowptr[N+1] esrc[E]
    // packed[E] bcnt/bbase/bcur[196]
    __half*   hnA    = (__half*)d_ws;
    __half*   hnB    = hnA + (size_t)NNODES * 32;
    float*    nA     = (float*)(hnB + (size_t)NNODES * 32);
    float*    nB     = nA + NNODES;
    int*      rowptr = (int*)(nB + NNODES);
    int*      esrc   = rowptr + NNODES + 1;
    unsigned* packed = (unsigned*)(esrc + NEDGES);
    int*      bcnt   = (int*)(packed + NEDGES);
    int*      bbase  = bcnt + NBUCK;
    int*      bcur   = bbase + NBUCK;

    dim3 blk(256);

    // CSR build (built once, used by both layers)
    hipMemsetAsync(bcnt, 0, NBUCK * sizeof(int), stream);
    k_bhist<<<NBINBLK, blk, 0, stream>>>(dst, bcnt);
    k_bscan<<<1, blk, 0, stream>>>(bcnt, bbase, bcur, rowptr);
    k_bin<<<NBINBLK, blk, 0, stream>>>(src, dst, bcur, packed);
    k_bucket<<<NBUCK, 512, 0, stream>>>(packed, bbase, bcnt, rowptr, esrc);

    k_lin1<<<2048, blk, 0, stream>>>(feat, w1, b1, hnA, nA);

    int gWave = NNODES / 4;   // exact
    k_agnn<false><<<gWave, blk, 0, stream>>>(hnA, nA, rowptr, esrc, betas, 0,
                                             hnB, nB, nullptr, nullptr, nullptr);
    k_agnn<true><<<gWave, blk, 0, stream>>>(hnB, nB, rowptr, esrc, betas, 1,
                                            nullptr, nullptr, w2, b2, out);
}

// Round 11
// 203.679 us; speedup vs baseline: 4.2572x; 1.0758x over previous
//
#include <hip/hip_runtime.h>
#include <hip/hip_fp16.h>

#define NNODES 100000
#define NEDGES 1600000

#define NBUCK  ((NNODES + 511) >> 9)      // 196 buckets of 512 nodes
#define BIN_EPT  16
#define BIN_TILE (256 * BIN_EPT)          // 4096 edges per bin block
#define NBINBLK  ((NEDGES + BIN_TILE - 1) / BIN_TILE)   // 391

static_assert(NNODES % 32 == 0, "kernels assume exact 32-node blocks");

static constexpr float EPS = 1e-12f;

__device__ __forceinline__ float2 h2f(unsigned u) {
    __half2 h = __builtin_bit_cast(__half2, u);
    return __half22float2(h);
}

#if defined(__has_builtin)
#if __has_builtin(__builtin_amdgcn_fdot2)
#define HAVE_FDOT2 1
#endif
#endif

__device__ __forceinline__ float dot8(uint2 a, uint2 b) {
#ifdef HAVE_FDOT2
    typedef _Float16 h2v __attribute__((ext_vector_type(2)));
    h2v ax = __builtin_bit_cast(h2v, a.x), ay = __builtin_bit_cast(h2v, a.y);
    h2v bx = __builtin_bit_cast(h2v, b.x), by = __builtin_bit_cast(h2v, b.y);
    return __builtin_amdgcn_fdot2(ax, bx,
           __builtin_amdgcn_fdot2(ay, by, 0.f, false), false);
#else
    float2 a01 = h2f(a.x), a23 = h2f(a.y);
    float2 b01 = h2f(b.x), b23 = h2f(b.y);
    return a01.x * b01.x + a01.y * b01.y + a23.x * b23.x + a23.y * b23.y;
#endif
}

// ---- DPP cross-lane reduction helpers (no LDS, no waitcnt) ----
template <int CTRL>
__device__ __forceinline__ float dppadd(float x) {
    int y = __builtin_amdgcn_update_dpp(0, __builtin_bit_cast(int, x),
                                        CTRL, 0xF, 0xF, true);
    return x + __builtin_bit_cast(float, y);
}
template <int CTRL>
__device__ __forceinline__ float dppmax(float x) {
    int y = __builtin_amdgcn_update_dpp(0, __builtin_bit_cast(int, x),
                                        CTRL, 0xF, 0xF, true);
    return fmaxf(x, __builtin_bit_cast(float, y));
}
__device__ __forceinline__ float swz16add(float x) {   // + lane^16 (exact)
    int y = __builtin_amdgcn_ds_swizzle(__builtin_bit_cast(int, x), 0x401F);
    return x + __builtin_bit_cast(float, y);
}
__device__ __forceinline__ float swz16max(float x) {
    int y = __builtin_amdgcn_ds_swizzle(__builtin_bit_cast(int, x), 0x401F);
    return fmaxf(x, __builtin_bit_cast(float, y));
}
// sum over an 8-lane group (xor1, xor2, half-mirror==xor4 after uniformity)
__device__ __forceinline__ float red8(float x) {
    x = dppadd<0xB1>(x);
    x = dppadd<0x4E>(x);
    x = dppadd<0x141>(x);
    return x;
}
// full 64-lane sum / max (exact)
__device__ __forceinline__ float red64(float x) {
    x = dppadd<0xB1>(x); x = dppadd<0x4E>(x);
    x = dppadd<0x141>(x); x = dppadd<0x128>(x);
    x = swz16add(x);
    x += __shfl_xor(x, 32);
    return x;
}
__device__ __forceinline__ float red64max(float x) {
    x = dppmax<0xB1>(x); x = dppmax<0x4E>(x);
    x = dppmax<0x141>(x); x = dppmax<0x128>(x);
    x = swz16max(x);
    x = fmaxf(x, __shfl_xor(x, 32));
    return x;
}
// sum over 32-lane half
__device__ __forceinline__ float red32(float x) {
    x = dppadd<0xB1>(x); x = dppadd<0x4E>(x);
    x = dppadd<0x141>(x); x = dppadd<0x128>(x);
    x = swz16add(x);
    return x;
}

// ---------------- CSR build: bucketed counting sort ----------------

__global__ __launch_bounds__(256) void k_bhist(
    const int* __restrict__ dst, int* __restrict__ bcnt)
{
    __shared__ int cnt[NBUCK];
    for (int i = threadIdx.x; i < NBUCK; i += 256) cnt[i] = 0;
    __syncthreads();
    int base = blockIdx.x * BIN_TILE;
    #pragma unroll
    for (int i = 0; i < BIN_EPT; ++i) {
        int k = base + i * 256 + threadIdx.x;
        if (k < NEDGES) atomicAdd(&cnt[dst[k] >> 9], 1);
    }
    __syncthreads();
    for (int i = threadIdx.x; i < NBUCK; i += 256)
        if (cnt[i]) atomicAdd(&bcnt[i], cnt[i]);
}

__global__ __launch_bounds__(256) void k_bscan(
    const int* __restrict__ bcnt, int* __restrict__ bbase,
    int* __restrict__ bcur, int* __restrict__ rowptr)
{
    __shared__ int ls[256];
    int t = threadIdx.x;
    ls[t] = (t < NBUCK) ? bcnt[t] : 0;
    __syncthreads();
    for (int off = 1; off < 256; off <<= 1) {
        int u = (t >= off) ? ls[t - off] : 0;
        __syncthreads();
        ls[t] += u;
        __syncthreads();
    }
    if (t < NBUCK) {
        int b = (t == 0) ? 0 : ls[t - 1];
        bbase[t] = b;
        bcur[t]  = b;
    }
    if (t == 0) rowptr[NNODES] = NEDGES;
}

// bin edges into bucket-contiguous packed[] : (dst&511)<<17 | src
__global__ __launch_bounds__(256) void k_bin(
    const int* __restrict__ src, const int* __restrict__ dst,
    int* __restrict__ bcur, unsigned* __restrict__ packed)
{
    __shared__ int cnt[NBUCK];
    __shared__ int gb[NBUCK];
    for (int i = threadIdx.x; i < NBUCK; i += 256) cnt[i] = 0;
    __syncthreads();
    unsigned pk[BIN_EPT];
    int bk[BIN_EPT];
    int base = blockIdx.x * BIN_TILE;
    #pragma unroll
    for (int i = 0; i < BIN_EPT; ++i) {
        int k = base + i * 256 + threadIdx.x;
        bk[i] = -1;
        if (k < NEDGES) {
            int d = dst[k], s = src[k];
            bk[i] = d >> 9;
            pk[i] = ((unsigned)(d & 511) << 17) | (unsigned)s;
            atomicAdd(&cnt[bk[i]], 1);
        }
    }
    __syncthreads();
    for (int i = threadIdx.x; i < NBUCK; i += 256) {
        int c = cnt[i];
        gb[i] = c ? atomicAdd(&bcur[i], c) : 0;
        cnt[i] = 0;
    }
    __syncthreads();
    #pragma unroll
    for (int i = 0; i < BIN_EPT; ++i) {
        if (bk[i] >= 0) {
            int pos = gb[bk[i]] + atomicAdd(&cnt[bk[i]], 1);
            packed[pos] = pk[i];
        }
    }
}

// one block per bucket: local count -> local scan -> rowptr + esrc scatter
__global__ __launch_bounds__(512) void k_bucket(
    const unsigned* __restrict__ packed, const int* __restrict__ bbase,
    const int* __restrict__ bcnt, int* __restrict__ rowptr,
    int* __restrict__ esrc)
{
    __shared__ int cnt[512];
    __shared__ int loc[512];
    int b = blockIdx.x, t = threadIdx.x;
    int base = bbase[b];
    int n = bcnt[b];
    cnt[t] = 0;
    __syncthreads();
    for (int i = t; i < n; i += 512)
        atomicAdd(&cnt[packed[base + i] >> 17], 1);
    __syncthreads();
    int v = cnt[t];
    loc[t] = v;
    __syncthreads();
    for (int off = 1; off < 512; off <<= 1) {
        int u = (t >= off) ? loc[t - off] : 0;
        __syncthreads();
        loc[t] += u;
        __syncthreads();
    }
    int excl = loc[t] - v;
    int node = b * 512 + t;
    if (node < NNODES) rowptr[node] = base + excl;
    cnt[t] = base + excl;          // absolute cursor
    __syncthreads();
    for (int i = t; i < n; i += 512) {
        unsigned p = packed[base + i];
        int pos = atomicAdd(&cnt[p >> 17], 1);
        esrc[pos] = (int)(p & 0x1FFFFu);
    }
}

// ---------------- compute kernels ----------------

// hn16[N,32] = fp16 normalized relu(feat @ w1^T + b1); nrm[N] = max(||h||,eps)
__global__ __launch_bounds__(256) void k_lin1(
    const float* __restrict__ feat, const float* __restrict__ w1,
    const float* __restrict__ b1, __half* __restrict__ hn16,
    float* __restrict__ nrm)
{
    __shared__ float w1s[32][129];
    __shared__ float fs[8][128];
    for (int i = threadIdx.x; i < 32 * 128; i += 256)
        w1s[i >> 7][i & 127] = w1[i];
    int r = threadIdx.x >> 5, c = threadIdx.x & 31;
    float bc = b1[c];
    const int ntiles = (NNODES + 7) / 8;
    for (int tile = blockIdx.x; tile < ntiles; tile += gridDim.x) {
        int row0 = tile * 8;
        __syncthreads();
        for (int i = threadIdx.x; i < 8 * 128; i += 256) {
            int rr = row0 + (i >> 7);
            fs[i >> 7][i & 127] = (rr < NNODES) ? feat[rr * 128 + (i & 127)] : 0.f;
        }
        __syncthreads();
        int row = row0 + r;
        float acc = bc;
        #pragma unroll
        for (int k = 0; k < 128; ++k) acc += fs[r][k] * w1s[c][k];
        acc = fmaxf(acc, 0.f);
        float ss = red32(acc * acc);          // sum over the 32 c-lanes
        if (row < NNODES) {
            float n = fmaxf(sqrtf(ss), EPS);
            hn16[(size_t)row * 32 + c] = __float2half(acc / n);
            if (c == 0) nrm[row] = n;
        }
    }
}

// One 8-lane group per node => 8 nodes/wave, 32 nodes/block. No cross-group
// merge: the group's den/acc ARE the node's. 2-edge unroll => 16 independent
// gather chains per wave. Constant-shift softmax (e in [-|b|,|b|]), DPP red8.
template <bool FUSED>
__global__ __launch_bounds__(256) void k_agnn(
    const __half* __restrict__ hn16, const float* __restrict__ nrm,
    const int* __restrict__ rowptr, const int* __restrict__ esrc,
    const float* __restrict__ betas, int layer,
    __half* __restrict__ hnout, float* __restrict__ nout,
    const float* __restrict__ w2, const float* __restrict__ b2,
    float* __restrict__ out)
{
    __shared__ float w2s[64][33];     // FUSED only
    __shared__ float osm[32][33];     // FUSED only: 32 node rows, padded
    int t = threadIdx.x;
    if (FUSED) {
        for (int i = t; i < 64 * 32; i += 256)
            w2s[i >> 5][i & 31] = w2[i];
    }
    int wid  = t >> 6;
    int lane = t & 63;
    int grp  = lane >> 3;            // group index = node slot within wave
    int c4   = lane & 7;             // 8B slot (4 halves) within the 64B row

    int node = blockIdx.x * 32 + wid * 8 + grp;   // exact: NNODES%32==0
    int start = rowptr[node], end = rowptr[node + 1];

    const uint2* hrow = reinterpret_cast<const uint2*>(hn16);
    float beta = betas[layer];
    float absb = fabsf(beta);
    uint2 qd = hrow[(size_t)node * 8 + c4];   // wave-contiguous 512B

    float den = 0.f;
    float4 acc = make_float4(0.f, 0.f, 0.f, 0.f);

    for (int i = start; i < end; i += 2) {
        bool has1 = (i + 1 < end);
        int s0 = esrc[i];
        int s1 = has1 ? esrc[i + 1] : s0;
        uint2 q0 = hrow[(size_t)s0 * 8 + c4];
        uint2 q1 = hrow[(size_t)s1 * 8 + c4];
        float n0 = nrm[s0], n1 = nrm[s1];
        float p0 = red8(dot8(q0, qd));            // 3 DPP adds
        float p1 = red8(dot8(q1, qd));
        float w0 = __expf(fmaf(beta, p0, -absb)); // exp(e - |beta|)
        float w1 = has1 ? __expf(fmaf(beta, p1, -absb)) : 0.f;
        float wn0 = w0 * n0, wn1 = w1 * n1;
        float2 a01 = h2f(q0.x), a23 = h2f(q0.y);
        float2 b01 = h2f(q1.x), b23 = h2f(q1.y);
        den += w0 + w1;
        acc.x += wn0 * a01.x + wn1 * b01.x;
        acc.y += wn0 * a01.y + wn1 * b01.y;
        acc.z += wn0 * a23.x + wn1 * b23.x;
        acc.w += wn0 * a23.y + wn1 * b23.y;
    }

    float inv = 1.f / fmaxf(den, EPS);
    float4 o;
    o.x = fmaxf(acc.x * inv, 0.f);
    o.y = fmaxf(acc.y * inv, 0.f);
    o.z = fmaxf(acc.z * inv, 0.f);
    o.w = fmaxf(acc.w * inv, 0.f);

    if (!FUSED) {
        float ss = red8(o.x * o.x + o.y * o.y + o.z * o.z + o.w * o.w);
        float nn = fmaxf(sqrtf(ss), EPS);
        float rn = 1.f / nn;
        __half2 lo = __floats2half2_rn(o.x * rn, o.y * rn);
        __half2 hi = __floats2half2_rn(o.z * rn, o.w * rn);
        uint2 q;
        q.x = __builtin_bit_cast(unsigned, lo);
        q.y = __builtin_bit_cast(unsigned, hi);
        reinterpret_cast<uint2*>(hnout)[(size_t)node * 8 + c4] = q;  // coalesced
        if (c4 == 0) nout[node] = nn;
    } else {
        int ln = wid * 8 + grp;
        float* orow = &osm[ln][c4 * 4];
        orow[0] = o.x; orow[1] = o.y; orow[2] = o.z; orow[3] = o.w;
        // preload this lane's W2 row into registers (reused for 8 nodes)
        float w2r[32];
        #pragma unroll
        for (int k = 0; k < 32; ++k) w2r[k] = w2s[lane][k];
        float b2l = b2[lane];
        __syncthreads();   // all 256 threads arrive (no early returns)
        int node0 = blockIdx.x * 32 + wid * 8;
        #pragma unroll
        for (int p = 0; p < 8; ++p) {
            const float* op = osm[wid * 8 + p];
            float a2 = b2l;
            #pragma unroll
            for (int k = 0; k < 32; ++k) a2 += op[k] * w2r[k];
            float mx = red64max(a2);
            float sm = red64(__expf(a2 - mx));
            out[(size_t)(node0 + p) * 64 + lane] = a2 - mx - __logf(sm);
        }
    }
}

extern "C" void kernel_launch(void* const* d_in, const int* in_sizes, int n_in,
                              void* d_out, int out_size, void* d_ws, size_t ws_size,
                              hipStream_t stream)
{
    const float* feat  = (const float*)d_in[0];
    const int*   src   = (const int*)d_in[1];
    const int*   dst   = (const int*)d_in[2];
    const float* w1    = (const float*)d_in[3];
    const float* b1    = (const float*)d_in[4];
    const float* betas = (const float*)d_in[5];
    const float* w2    = (const float*)d_in[6];
    const float* b2    = (const float*)d_in[7];
    float* out = (float*)d_out;

    // workspace: hnA[6.4MB] hnB[6.4MB] nA[N] nB[N] rowptr[N+1] esrc[E]
    // packed[E] bcnt/bbase/bcur[196]
    __half*   hnA    = (__half*)d_ws;
    __half*   hnB    = hnA + (size_t)NNODES * 32;
    float*    nA     = (float*)(hnB + (size_t)NNODES * 32);
    float*    nB     = nA + NNODES;
    int*      rowptr = (int*)(nB + NNODES);
    int*      esrc   = rowptr + NNODES + 1;
    unsigned* packed = (unsigned*)(esrc + NEDGES);
    int*      bcnt   = (int*)(packed + NEDGES);
    int*      bbase  = bcnt + NBUCK;
    int*      bcur   = bbase + NBUCK;

    dim3 blk(256);

    // CSR build (built once, used by both layers)
    hipMemsetAsync(bcnt, 0, NBUCK * sizeof(int), stream);
    k_bhist<<<NBINBLK, blk, 0, stream>>>(dst, bcnt);
    k_bscan<<<1, blk, 0, stream>>>(bcnt, bbase, bcur, rowptr);
    k_bin<<<NBINBLK, blk, 0, stream>>>(src, dst, bcur, packed);
    k_bucket<<<NBUCK, 512, 0, stream>>>(packed, bbase, bcnt, rowptr, esrc);

    k_lin1<<<2048, blk, 0, stream>>>(feat, w1, b1, hnA, nA);

    int gBlk = NNODES / 32;   // exact
    k_agnn<false><<<gBlk, blk, 0, stream>>>(hnA, nA, rowptr, esrc, betas, 0,
                                            hnB, nB, nullptr, nullptr, nullptr);
    k_agnn<true><<<gBlk, blk, 0, stream>>>(hnB, nB, rowptr, esrc, betas, 1,
                                           nullptr, nullptr, w2, b2, out);
}

// Round 12
// 182.330 us; speedup vs baseline: 4.7557x; 1.1171x over previous
//
#include <hip/hip_runtime.h>
#include <hip/hip_fp16.h>

#define NNODES 100000
#define NEDGES 1600000

#define NBUCK  ((NNODES + 511) >> 9)      // 196 buckets of 512 nodes
#define BIN_EPT  16
#define BIN_TILE (256 * BIN_EPT)          // 4096 edges per bin block
#define NBINBLK  ((NEDGES + BIN_TILE - 1) / BIN_TILE)   // 391

static_assert(NNODES % 32 == 0, "kernels assume exact 32-node blocks");

static constexpr float EPS = 1e-12f;

__device__ __forceinline__ float2 h2f(unsigned u) {
    __half2 h = __builtin_bit_cast(__half2, u);
    return __half22float2(h);
}

#if defined(__has_builtin)
#if __has_builtin(__builtin_amdgcn_fdot2)
#define HAVE_FDOT2 1
#endif
#endif

__device__ __forceinline__ float dot8(uint2 a, uint2 b) {
#ifdef HAVE_FDOT2
    typedef _Float16 h2v __attribute__((ext_vector_type(2)));
    h2v ax = __builtin_bit_cast(h2v, a.x), ay = __builtin_bit_cast(h2v, a.y);
    h2v bx = __builtin_bit_cast(h2v, b.x), by = __builtin_bit_cast(h2v, b.y);
    return __builtin_amdgcn_fdot2(ax, bx,
           __builtin_amdgcn_fdot2(ay, by, 0.f, false), false);
#else
    float2 a01 = h2f(a.x), a23 = h2f(a.y);
    float2 b01 = h2f(b.x), b23 = h2f(b.y);
    return a01.x * b01.x + a01.y * b01.y + a23.x * b23.x + a23.y * b23.y;
#endif
}

// ---- DPP cross-lane reduction helpers (no LDS, no waitcnt) ----
template <int CTRL>
__device__ __forceinline__ float dppadd(float x) {
    int y = __builtin_amdgcn_update_dpp(0, __builtin_bit_cast(int, x),
                                        CTRL, 0xF, 0xF, true);
    return x + __builtin_bit_cast(float, y);
}
template <int CTRL>
__device__ __forceinline__ float dppmax(float x) {
    int y = __builtin_amdgcn_update_dpp(0, __builtin_bit_cast(int, x),
                                        CTRL, 0xF, 0xF, true);
    return fmaxf(x, __builtin_bit_cast(float, y));
}
__device__ __forceinline__ float swz16add(float x) {   // + lane^16 (exact)
    int y = __builtin_amdgcn_ds_swizzle(__builtin_bit_cast(int, x), 0x401F);
    return x + __builtin_bit_cast(float, y);
}
__device__ __forceinline__ float swz16max(float x) {
    int y = __builtin_amdgcn_ds_swizzle(__builtin_bit_cast(int, x), 0x401F);
    return fmaxf(x, __builtin_bit_cast(float, y));
}
// sum over an 8-lane group (xor1, xor2, half-mirror==xor4 after uniformity)
__device__ __forceinline__ float red8(float x) {
    x = dppadd<0xB1>(x);
    x = dppadd<0x4E>(x);
    x = dppadd<0x141>(x);
    return x;
}
// full 64-lane sum / max (exact)
__device__ __forceinline__ float red64(float x) {
    x = dppadd<0xB1>(x); x = dppadd<0x4E>(x);
    x = dppadd<0x141>(x); x = dppadd<0x128>(x);
    x = swz16add(x);
    x += __shfl_xor(x, 32);
    return x;
}
__device__ __forceinline__ float red64max(float x) {
    x = dppmax<0xB1>(x); x = dppmax<0x4E>(x);
    x = dppmax<0x141>(x); x = dppmax<0x128>(x);
    x = swz16max(x);
    x = fmaxf(x, __shfl_xor(x, 32));
    return x;
}

// ---------------- CSR build: bucketed counting sort ----------------

__global__ __launch_bounds__(256) void k_bhist(
    const int* __restrict__ dst, int* __restrict__ bcnt)
{
    __shared__ int cnt[NBUCK];
    for (int i = threadIdx.x; i < NBUCK; i += 256) cnt[i] = 0;
    __syncthreads();
    int base = blockIdx.x * BIN_TILE;
    #pragma unroll
    for (int i = 0; i < BIN_EPT; ++i) {
        int k = base + i * 256 + threadIdx.x;
        if (k < NEDGES) atomicAdd(&cnt[dst[k] >> 9], 1);
    }
    __syncthreads();
    for (int i = threadIdx.x; i < NBUCK; i += 256)
        if (cnt[i]) atomicAdd(&bcnt[i], cnt[i]);
}

__global__ __launch_bounds__(256) void k_bscan(
    const int* __restrict__ bcnt, int* __restrict__ bbase,
    int* __restrict__ bcur, int* __restrict__ rowptr)
{
    __shared__ int ls[256];
    int t = threadIdx.x;
    ls[t] = (t < NBUCK) ? bcnt[t] : 0;
    __syncthreads();
    for (int off = 1; off < 256; off <<= 1) {
        int u = (t >= off) ? ls[t - off] : 0;
        __syncthreads();
        ls[t] += u;
        __syncthreads();
    }
    if (t < NBUCK) {
        int b = (t == 0) ? 0 : ls[t - 1];
        bbase[t] = b;
        bcur[t]  = b;
    }
    if (t == 0) rowptr[NNODES] = NEDGES;
}

// bin edges into bucket-contiguous packed[] : (dst&511)<<17 | src
__global__ __launch_bounds__(256) void k_bin(
    const int* __restrict__ src, const int* __restrict__ dst,
    int* __restrict__ bcur, unsigned* __restrict__ packed)
{
    __shared__ int cnt[NBUCK];
    __shared__ int gb[NBUCK];
    for (int i = threadIdx.x; i < NBUCK; i += 256) cnt[i] = 0;
    __syncthreads();
    unsigned pk[BIN_EPT];
    int bk[BIN_EPT];
    int base = blockIdx.x * BIN_TILE;
    #pragma unroll
    for (int i = 0; i < BIN_EPT; ++i) {
        int k = base + i * 256 + threadIdx.x;
        bk[i] = -1;
        if (k < NEDGES) {
            int d = dst[k], s = src[k];
            bk[i] = d >> 9;
            pk[i] = ((unsigned)(d & 511) << 17) | (unsigned)s;
            atomicAdd(&cnt[bk[i]], 1);
        }
    }
    __syncthreads();
    for (int i = threadIdx.x; i < NBUCK; i += 256) {
        int c = cnt[i];
        gb[i] = c ? atomicAdd(&bcur[i], c) : 0;
        cnt[i] = 0;
    }
    __syncthreads();
    #pragma unroll
    for (int i = 0; i < BIN_EPT; ++i) {
        if (bk[i] >= 0) {
            int pos = gb[bk[i]] + atomicAdd(&cnt[bk[i]], 1);
            packed[pos] = pk[i];
        }
    }
}

// one block per bucket: local count -> local scan -> rowptr + esrc scatter
__global__ __launch_bounds__(512) void k_bucket(
    const unsigned* __restrict__ packed, const int* __restrict__ bbase,
    const int* __restrict__ bcnt, int* __restrict__ rowptr,
    int* __restrict__ esrc)
{
    __shared__ int cnt[512];
    __shared__ int loc[512];
    int b = blockIdx.x, t = threadIdx.x;
    int base = bbase[b];
    int n = bcnt[b];
    cnt[t] = 0;
    __syncthreads();
    for (int i = t; i < n; i += 512)
        atomicAdd(&cnt[packed[base + i] >> 17], 1);
    __syncthreads();
    int v = cnt[t];
    loc[t] = v;
    __syncthreads();
    for (int off = 1; off < 512; off <<= 1) {
        int u = (t >= off) ? loc[t - off] : 0;
        __syncthreads();
        loc[t] += u;
        __syncthreads();
    }
    int excl = loc[t] - v;
    int node = b * 512 + t;
    if (node < NNODES) rowptr[node] = base + excl;
    cnt[t] = base + excl;          // absolute cursor
    __syncthreads();
    for (int i = t; i < n; i += 512) {
        unsigned p = packed[base + i];
        int pos = atomicAdd(&cnt[p >> 17], 1);
        esrc[pos] = (int)(p & 0x1FFFFu);
    }
}

// ---------------- compute kernels ----------------

// Row-per-thread GEMV: hn16[N,32] = fp16 normalized relu(feat @ w1^T + b1);
// nrm[N] = max(||h||,eps). feat row global->regs (32 hoisted float4 loads);
// w1 in LDS, read at wave-uniform addresses (free broadcast).
__global__ __launch_bounds__(256) void k_lin1(
    const float* __restrict__ feat, const float* __restrict__ w1,
    const float* __restrict__ b1, __half* __restrict__ hn16,
    float* __restrict__ nrm)
{
    __shared__ float4 w1s[32][32];     // w1s[c][k4], 16KB, broadcast reads
    int t = threadIdx.x;
    {
        const float4* w4 = reinterpret_cast<const float4*>(w1);
        float4* ws = &w1s[0][0];
        #pragma unroll
        for (int i = 0; i < 4; ++i) ws[t + i * 256] = w4[t + i * 256];
    }
    __syncthreads();

    int row = blockIdx.x * 256 + t;
    if (row >= NNODES) return;

    const float4* fr = reinterpret_cast<const float4*>(feat + (size_t)row * 128);
    float4 f[32];
    #pragma unroll
    for (int k = 0; k < 32; ++k) f[k] = fr[k];      // hoisted, 512B in flight

    float acc[32];
    #pragma unroll
    for (int c = 0; c < 32; ++c) acc[c] = b1[c];    // uniform -> s_load

    #pragma unroll
    for (int k = 0; k < 32; ++k) {
        #pragma unroll
        for (int c = 0; c < 32; ++c) {
            float4 w = w1s[c][k];                   // wave-uniform broadcast
            acc[c] = fmaf(f[k].x, w.x, acc[c]);
            acc[c] = fmaf(f[k].y, w.y, acc[c]);
            acc[c] = fmaf(f[k].z, w.z, acc[c]);
            acc[c] = fmaf(f[k].w, w.w, acc[c]);
        }
    }

    float ss = 0.f;
    #pragma unroll
    for (int c = 0; c < 32; ++c) {
        acc[c] = fmaxf(acc[c], 0.f);
        ss = fmaf(acc[c], acc[c], ss);
    }
    float n = fmaxf(sqrtf(ss), EPS);
    float rn = 1.f / n;
    unsigned q[16];
    #pragma unroll
    for (int j = 0; j < 16; ++j) {
        __half2 hh = __floats2half2_rn(acc[2 * j] * rn, acc[2 * j + 1] * rn);
        q[j] = __builtin_bit_cast(unsigned, hh);
    }
    uint4* o4 = reinterpret_cast<uint4*>(hn16 + (size_t)row * 32);
    o4[0] = make_uint4(q[0],  q[1],  q[2],  q[3]);
    o4[1] = make_uint4(q[4],  q[5],  q[6],  q[7]);
    o4[2] = make_uint4(q[8],  q[9],  q[10], q[11]);
    o4[3] = make_uint4(q[12], q[13], q[14], q[15]);
    nrm[row] = n;
}

// One 8-lane group per node => 8 nodes/wave, 32 nodes/block. No cross-group
// merge: the group's den/acc ARE the node's. 2-edge unroll => 16 independent
// gather chains per wave. Constant-shift softmax (e in [-|b|,|b|]), DPP red8.
template <bool FUSED>
__global__ __launch_bounds__(256) void k_agnn(
    const __half* __restrict__ hn16, const float* __restrict__ nrm,
    const int* __restrict__ rowptr, const int* __restrict__ esrc,
    const float* __restrict__ betas, int layer,
    __half* __restrict__ hnout, float* __restrict__ nout,
    const float* __restrict__ w2, const float* __restrict__ b2,
    float* __restrict__ out)
{
    __shared__ float w2s[64][33];     // FUSED only
    __shared__ float osm[32][33];     // FUSED only: 32 node rows, padded
    int t = threadIdx.x;
    if (FUSED) {
        for (int i = t; i < 64 * 32; i += 256)
            w2s[i >> 5][i & 31] = w2[i];
    }
    int wid  = t >> 6;
    int lane = t & 63;
    int grp  = lane >> 3;            // group index = node slot within wave
    int c4   = lane & 7;             // 8B slot (4 halves) within the 64B row

    int node = blockIdx.x * 32 + wid * 8 + grp;   // exact: NNODES%32==0
    int start = rowptr[node], end = rowptr[node + 1];

    const uint2* hrow = reinterpret_cast<const uint2*>(hn16);
    float beta = betas[layer];
    float absb = fabsf(beta);
    uint2 qd = hrow[(size_t)node * 8 + c4];   // wave-contiguous 512B

    float den = 0.f;
    float4 acc = make_float4(0.f, 0.f, 0.f, 0.f);

    for (int i = start; i < end; i += 2) {
        bool has1 = (i + 1 < end);
        int s0 = esrc[i];
        int s1 = has1 ? esrc[i + 1] : s0;
        uint2 q0 = hrow[(size_t)s0 * 8 + c4];
        uint2 q1 = hrow[(size_t)s1 * 8 + c4];
        float n0 = nrm[s0], n1 = nrm[s1];
        float p0 = red8(dot8(q0, qd));            // 3 DPP adds
        float p1 = red8(dot8(q1, qd));
        float w0 = __expf(fmaf(beta, p0, -absb)); // exp(e - |beta|)
        float w1 = has1 ? __expf(fmaf(beta, p1, -absb)) : 0.f;
        float wn0 = w0 * n0, wn1 = w1 * n1;
        float2 a01 = h2f(q0.x), a23 = h2f(q0.y);
        float2 b01 = h2f(q1.x), b23 = h2f(q1.y);
        den += w0 + w1;
        acc.x += wn0 * a01.x + wn1 * b01.x;
        acc.y += wn0 * a01.y + wn1 * b01.y;
        acc.z += wn0 * a23.x + wn1 * b23.x;
        acc.w += wn0 * a23.y + wn1 * b23.y;
    }

    float inv = 1.f / fmaxf(den, EPS);
    float4 o;
    o.x = fmaxf(acc.x * inv, 0.f);
    o.y = fmaxf(acc.y * inv, 0.f);
    o.z = fmaxf(acc.z * inv, 0.f);
    o.w = fmaxf(acc.w * inv, 0.f);

    if (!FUSED) {
        float ss = red8(o.x * o.x + o.y * o.y + o.z * o.z + o.w * o.w);
        float nn = fmaxf(sqrtf(ss), EPS);
        float rn = 1.f / nn;
        __half2 lo = __floats2half2_rn(o.x * rn, o.y * rn);
        __half2 hi = __floats2half2_rn(o.z * rn, o.w * rn);
        uint2 q;
        q.x = __builtin_bit_cast(unsigned, lo);
        q.y = __builtin_bit_cast(unsigned, hi);
        reinterpret_cast<uint2*>(hnout)[(size_t)node * 8 + c4] = q;  // coalesced
        if (c4 == 0) nout[node] = nn;
    } else {
        int ln = wid * 8 + grp;
        float* orow = &osm[ln][c4 * 4];
        orow[0] = o.x; orow[1] = o.y; orow[2] = o.z; orow[3] = o.w;
        // preload this lane's W2 row into registers (reused for 8 nodes)
        float w2r[32];
        #pragma unroll
        for (int k = 0; k < 32; ++k) w2r[k] = w2s[lane][k];
        float b2l = b2[lane];
        __syncthreads();   // all 256 threads arrive (no early returns)
        int node0 = blockIdx.x * 32 + wid * 8;
        #pragma unroll
        for (int p = 0; p < 8; ++p) {
            const float* op = osm[wid * 8 + p];
            float a2 = b2l;
            #pragma unroll
            for (int k = 0; k < 32; ++k) a2 += op[k] * w2r[k];
            float mx = red64max(a2);
            float sm = red64(__expf(a2 - mx));
            out[(size_t)(node0 + p) * 64 + lane] = a2 - mx - __logf(sm);
        }
    }
}

extern "C" void kernel_launch(void* const* d_in, const int* in_sizes, int n_in,
                              void* d_out, int out_size, void* d_ws, size_t ws_size,
                              hipStream_t stream)
{
    const float* feat  = (const float*)d_in[0];
    const int*   src   = (const int*)d_in[1];
    const int*   dst   = (const int*)d_in[2];
    const float* w1    = (const float*)d_in[3];
    const float* b1    = (const float*)d_in[4];
    const float* betas = (const float*)d_in[5];
    const float* w2    = (const float*)d_in[6];
    const float* b2    = (const float*)d_in[7];
    float* out = (float*)d_out;

    // workspace: hnA[6.4MB] hnB[6.4MB] nA[N] nB[N] rowptr[N+1] esrc[E]
    // packed[E] bcnt/bbase/bcur[196]
    __half*   hnA    = (__half*)d_ws;
    __half*   hnB    = hnA + (size_t)NNODES * 32;
    float*    nA     = (float*)(hnB + (size_t)NNODES * 32);
    float*    nB     = nA + NNODES;
    int*      rowptr = (int*)(nB + NNODES);
    int*      esrc   = rowptr + NNODES + 1;
    unsigned* packed = (unsigned*)(esrc + NEDGES);
    int*      bcnt   = (int*)(packed + NEDGES);
    int*      bbase  = bcnt + NBUCK;
    int*      bcur   = bbase + NBUCK;

    dim3 blk(256);

    // CSR build (built once, used by both layers)
    hipMemsetAsync(bcnt, 0, NBUCK * sizeof(int), stream);
    k_bhist<<<NBINBLK, blk, 0, stream>>>(dst, bcnt);
    k_bscan<<<1, blk, 0, stream>>>(bcnt, bbase, bcur, rowptr);
    k_bin<<<NBINBLK, blk, 0, stream>>>(src, dst, bcur, packed);
    k_bucket<<<NBUCK, 512, 0, stream>>>(packed, bbase, bcnt, rowptr, esrc);

    k_lin1<<<(NNODES + 255) / 256, blk, 0, stream>>>(feat, w1, b1, hnA, nA);

    int gBlk = NNODES / 32;   // exact
    k_agnn<false><<<gBlk, blk, 0, stream>>>(hnA, nA, rowptr, esrc, betas, 0,
                                            hnB, nB, nullptr, nullptr, nullptr);
    k_agnn<true><<<gBlk, blk, 0, stream>>>(hnB, nB, rowptr, esrc, betas, 1,
                                           nullptr, nullptr, w2, b2, out);
}